// Round 9
// baseline (990.920 us; speedup 1.0000x reference)
//
#include <hip/hip_runtime.h>
#include <cstdint>
#include <cstddef>

#define B_ 2
#define S_ 1024
#define H_ 2048
#define HV_ 32
#define HK_ 16
#define DK_ 128
#define DV_ 128
#define CC_ 8192
#define KEYDIM_ 2048
#define VALDIM_ 4096
#define NC_ 16          // chunks
#define CS_ 64          // chunk size
#define NBIG 12416      // fused GEMM1 N: 8192 qkv + 4096 z + 32 b + 32 a + 64 pad

typedef __attribute__((ext_vector_type(8))) short bf16x8;
typedef __attribute__((ext_vector_type(4))) float f32x4;

__device__ __forceinline__ ushort f2bf_rne(float x) {
  union { float f; uint32_t u; } c; c.f = x;
  uint32_t u = c.u + 0x7FFFu + ((c.u >> 16) & 1u);
  return (ushort)(u >> 16);
}

// async 16B global->LDS (DMA; LDS dest = wave-uniform base + lane*16)
__device__ __forceinline__ void gld16(const void* g, void* l) {
  __builtin_amdgcn_global_load_lds(
      (const __attribute__((address_space(1))) void*)g,
      (__attribute__((address_space(3))) void*)l, 16, 0, 0);
}

// ---------------------------------------------------------------------------
// fp32 -> bf16 convert (n multiple of 1024)
// ---------------------------------------------------------------------------
__global__ void f2bf_kernel(const float* __restrict__ in, ushort* __restrict__ out, int n) {
  int i = (blockIdx.x * 256 + threadIdx.x) * 4;
  if (i >= n) return;
  float4 v = *(const float4*)(in + i);
  ushort4 o;
  o.x = f2bf_rne(v.x); o.y = f2bf_rne(v.y);
  o.z = f2bf_rne(v.z); o.w = f2bf_rne(v.w);
  *(ushort4*)(out + i) = o;
}

// ---------------------------------------------------------------------------
// wcat: build concatenated bf16 weight (NBIG, H): [W_qkv; W_z; W_b; W_a; 0]
// ---------------------------------------------------------------------------
__global__ void wcat_kernel(const float* __restrict__ Wqkv, const float* __restrict__ Wz,
                            const float* __restrict__ Wb, const float* __restrict__ Wa,
                            ushort* __restrict__ out) {
  int i = (blockIdx.x * 256 + threadIdx.x) * 4;
  if (i >= NBIG * H_) return;
  int n = i >> 11;           // / H_
  int k = i & (H_ - 1);
  float4 v = make_float4(0.f, 0.f, 0.f, 0.f);
  if (n < 8192)       v = *(const float4*)(Wqkv + (size_t)n * H_ + k);
  else if (n < 12288) v = *(const float4*)(Wz + (size_t)(n - 8192) * H_ + k);
  else if (n < 12320) v = *(const float4*)(Wb + (size_t)(n - 12288) * H_ + k);
  else if (n < 12352) v = *(const float4*)(Wa + (size_t)(n - 12320) * H_ + k);
  ushort4 o;
  o.x = f2bf_rne(v.x); o.y = f2bf_rne(v.y);
  o.z = f2bf_rne(v.z); o.w = f2bf_rne(v.w);
  *(ushort4*)(out + i) = o;
}

// ---------------------------------------------------------------------------
// bf16 MFMA GEMM (NT): C[m][n] = sum_k A[m][k]*B[n][k]. M = 2048 (16 m-tiles),
// N % 128, K % 32. 128x128 tile, BK=32, double-buffered (32 KB LDS total ->
// 5 blocks/CU; barrier drains hidden by sibling blocks). 1D grid with
// XCD-aware decode: xcd = id&7 selects the n-column group so all 16 m-tiles
// sharing a B-tile land on one XCD's L2.
// grid = 8 * 16 * ceil(Ntiles/8); blocks with n >= Ntiles exit.
// ---------------------------------------------------------------------------
__global__ __launch_bounds__(256) void gemm_bf16_nt(
    const ushort* __restrict__ A, const ushort* __restrict__ B,
    float* __restrict__ C, int N, int K, int Ntiles)
{
  int id = blockIdx.x;
  int xcd = id & 7;
  int s = id >> 3;
  int nt = xcd + 8 * (s >> 4);    // n-tile
  int mt = s & 15;                // m-tile
  if (nt >= Ntiles) return;

  __shared__ ushort sL[2][2][4096];   // [buf][A/B][8 segs x 512]
  int t = threadIdx.x;
  int wave = t >> 6, lane = t & 63;
  int wm = wave >> 1, wn = wave & 1;
  int lrow = lane & 15, quad = lane >> 4;

  f32x4 acc[4][4];
  #pragma unroll
  for (int i = 0; i < 4; i++)
    #pragma unroll
    for (int j = 0; j < 4; j++)
      #pragma unroll
      for (int r = 0; r < 4; r++) acc[i][j][r] = 0.f;

  int seg0 = wave * 2, seg1 = wave * 2 + 1;
  const ushort* aS0 = A + (size_t)(mt * 128 + seg0 * 16 + lrow) * K + quad * 8;
  const ushort* aS1 = A + (size_t)(mt * 128 + seg1 * 16 + lrow) * K + quad * 8;
  const ushort* bS0 = B + (size_t)(nt * 128 + seg0 * 16 + lrow) * K + quad * 8;
  const ushort* bS1 = B + (size_t)(nt * 128 + seg1 * 16 + lrow) * K + quad * 8;

  // prologue: stage tile 0 into buf 0
  gld16(aS0, &sL[0][0][seg0 * 512]);
  gld16(aS1, &sL[0][0][seg1 * 512]);
  gld16(bS0, &sL[0][1][seg0 * 512]);
  gld16(bS1, &sL[0][1][seg1 * 512]);
  __syncthreads();

  const int NK = K >> 5;
  for (int it = 0; it < NK; it++) {
    if (it + 1 < NK) {
      int k0 = (it + 1) * 32;
      int nb = (it + 1) & 1;
      gld16(aS0 + k0, &sL[nb][0][seg0 * 512]);
      gld16(aS1 + k0, &sL[nb][0][seg1 * 512]);
      gld16(bS0 + k0, &sL[nb][1][seg0 * 512]);
      gld16(bS1 + k0, &sL[nb][1][seg1 * 512]);
    }
    const ushort* bufA = &sL[it & 1][0][0];
    const ushort* bufB = &sL[it & 1][1][0];
    bf16x8 af[4], bfr[4];
    #pragma unroll
    for (int i = 0; i < 4; i++)
      af[i] = *(const bf16x8*)(bufA + (wm * 4 + i) * 512 + lane * 8);
    #pragma unroll
    for (int j = 0; j < 4; j++)
      bfr[j] = *(const bf16x8*)(bufB + (wn * 4 + j) * 512 + lane * 8);
    #pragma unroll
    for (int i = 0; i < 4; i++)
      #pragma unroll
      for (int j = 0; j < 4; j++)
        acc[i][j] = __builtin_amdgcn_mfma_f32_16x16x32_bf16(af[i], bfr[j], acc[i][j], 0, 0, 0);
    __syncthreads();
  }

  #pragma unroll
  for (int i = 0; i < 4; i++) {
    int m_base = mt * 128 + wm * 64 + i * 16 + quad * 4;
    #pragma unroll
    for (int j = 0; j < 4; j++) {
      int n = nt * 128 + wn * 64 + j * 16 + lrow;
      #pragma unroll
      for (int rr = 0; rr < 4; rr++)
        C[(size_t)(m_base + rr) * N + n] = acc[i][j][rr];
    }
  }
}

// ---------------------------------------------------------------------------
// conv_state_new[b][c][j] = mixed_qkv[b][S-3+j][c]  (from (B,S,NBIG) C-matrix)
// ---------------------------------------------------------------------------
__global__ void convstate_kernel(const float* __restrict__ Cbig,
                                 float* __restrict__ out)
{
  int idx = blockIdx.x * blockDim.x + threadIdx.x;
  if (idx >= B_ * CC_ * 3) return;
  int j = idx % 3;
  int c = (idx / 3) % CC_;
  int b = idx / (3 * CC_);
  out[idx] = Cbig[((size_t)(b * S_ + (S_ - 3 + j))) * NBIG + c];
}

// ---------------------------------------------------------------------------
// prep_qkv: conv(K=4)+silu; l2norm q/k heads. qkv read from C-matrix cols 0..8191
// ---------------------------------------------------------------------------
__global__ __launch_bounds__(128) void prep_qkv(
    const float* __restrict__ Cbig, const float* __restrict__ conv_state,
    const float* __restrict__ conv_w,
    float* __restrict__ Qn, float* __restrict__ Kn, float* __restrict__ Vb)
{
  int group = blockIdx.x, s = blockIdx.y, b = blockIdx.z;
  int t = threadIdx.x;
  int c = group * 128 + t;
  float acc = 0.f;
  #pragma unroll
  for (int kk = 0; kk < 4; kk++) {
    int sp = s - 3 + kk;
    float x = (sp < 0) ? conv_state[((size_t)(b * CC_ + c)) * 3 + (3 + sp)]
                       : Cbig[((size_t)(b * S_ + sp)) * NBIG + c];
    acc += conv_w[c * 4 + kk] * x;
  }
  float val = acc / (1.f + __expf(-acc));   // silu

  if (group < 32) {
    __shared__ float red2[2];
    float p = val * val;
    #pragma unroll
    for (int off = 32; off > 0; off >>= 1) p += __shfl_xor(p, off);
    if ((t & 63) == 0) red2[t >> 6] = p;
    __syncthreads();
    float r = rsqrtf(red2[0] + red2[1] + 1e-6f);
    if (group < 16) {
      r *= 0.08838834764831845f;  // 128^-0.5
      Qn[(((size_t)(b * HK_ + group)) * S_ + s) * DK_ + t] = val * r;
    } else {
      Kn[(((size_t)(b * HK_ + (group - 16))) * S_ + s) * DK_ + t] = val * r;
    }
  } else {
    Vb[(((size_t)(b * HV_ + (group - 32))) * S_ + s) * DV_ + t] = val;
  }
}

// ---------------------------------------------------------------------------
// prep_gb: g/beta from C-matrix cols 12288..12351
// ---------------------------------------------------------------------------
__global__ void prep_gb(const float* __restrict__ Cbig,
                        const float* __restrict__ A_log, const float* __restrict__ dt_bias,
                        float* __restrict__ g_buf, float* __restrict__ beta_buf)
{
  int idx = blockIdx.x * blockDim.x + threadIdx.x;
  if (idx >= B_ * HV_ * S_) return;
  int s = idx & (S_ - 1);
  int hv = (idx >> 10) & 31;
  int b = idx >> 15;
  float bv = Cbig[((size_t)(b * S_ + s)) * NBIG + 12288 + hv];
  float av = Cbig[((size_t)(b * S_ + s)) * NBIG + 12320 + hv];
  float x = av + dt_bias[hv];
  float sp = (x > 20.f) ? x : log1pf(__expf(x));
  g_buf[idx] = -__expf(A_log[hv]) * sp;
  beta_buf[idx] = 1.f / (1.f + __expf(-bv));
}

// ---------------------------------------------------------------------------
// cp_kernel: per (b,hv,chunk). G cumsum, M, A, Tinv, Kc, D0.
// ---------------------------------------------------------------------------
__device__ __forceinline__ int swf4(int r, int f) { return r * 32 + (f ^ (r & 31)); }
__device__ __forceinline__ int swf1(int r, int k) {
  return r * 128 + 4 * ((k >> 2) ^ (r & 31)) + (k & 3);
}

__global__ __launch_bounds__(256) void cp_kernel(
    const float* __restrict__ Qn, const float* __restrict__ Kn,
    const float* __restrict__ Vb,
    const float* __restrict__ g_buf, const float* __restrict__ beta_buf,
    float* __restrict__ G_buf, float* __restrict__ M_buf,
    float* __restrict__ KcD, float* __restrict__ D0p)
{
  __shared__ float sK[64 * 128];
  __shared__ float sX[32 * 128];
  __shared__ float sT[64 * 64];
  float* sG  = sT;
  float* sBe = sT + 64;
  float* sA  = sX;
  float* tTw = sX;
  float* tTb = sX;
  float4* sK4 = (float4*)sK;
  float4* sX4 = (float4*)sX;

  const int ch = blockIdx.x;
  const int bh = ch / NC_, c = ch % NC_;
  const int b = bh >> 5, hv = bh & 31, hk = hv >> 1;
  const int s0 = c * CS_;
  const int t = threadIdx.x;
  const size_t gOff = (size_t)bh * S_ + s0;

  float Gw0 = 0.f, Bw0 = 0.f;
  if (t < 64) {
    float gi = g_buf[gOff + t];
    Gw0 = gi;
    #pragma unroll
    for (int off = 1; off < 64; off <<= 1) {
      float o = __shfl_up(Gw0, off);
      if (t >= off) Gw0 += o;
    }
    G_buf[gOff + t] = Gw0;
    sG[t] = Gw0;
    Bw0 = beta_buf[gOff + t];
    sBe[t] = Bw0;
  }
  {
    const float4* src = (const float4*)(Kn + ((size_t)(b * HK_ + hk) * S_ + s0) * DK_);
    #pragma unroll
    for (int u = 0; u < 8; u++) {
      int idx = u * 256 + t;
      sK4[swf4(idx >> 5, idx & 31)] = src[idx];
    }
  }
  __syncthreads();

  const float4* qsrc = (const float4*)(Qn + ((size_t)(b * HK_ + hk) * S_ + s0) * DK_);
  {
    int ti2 = t >> 4, tj = t & 15;
    for (int h = 0; h < 2; h++) {
      #pragma unroll
      for (int u = 0; u < 4; u++) {
        int idx = u * 256 + t;
        sX4[swf4(idx >> 5, idx & 31)] = qsrc[h * 1024 + idx];
      }
      __syncthreads();
      float accM[2][4];
      #pragma unroll
      for (int a = 0; a < 2; a++)
        #pragma unroll
        for (int e = 0; e < 4; e++) accM[a][e] = 0.f;
      for (int k4 = 0; k4 < 32; k4++) {
        float4 qv[2], kv[4];
        qv[0] = sX4[swf4(ti2, k4)];
        qv[1] = sX4[swf4(ti2 + 16, k4)];
        #pragma unroll
        for (int e = 0; e < 4; e++) kv[e] = sK4[swf4(tj + 16 * e, k4)];
        #pragma unroll
        for (int a = 0; a < 2; a++)
          #pragma unroll
          for (int e = 0; e < 4; e++)
            accM[a][e] += qv[a].x * kv[e].x + qv[a].y * kv[e].y +
                          qv[a].z * kv[e].z + qv[a].w * kv[e].w;
      }
      #pragma unroll
      for (int a = 0; a < 2; a++) {
        int iG = h * 32 + ti2 + 16 * a;
        float Gi = sG[iG];
        #pragma unroll
        for (int e = 0; e < 4; e++) {
          int j = tj + 16 * e;
          float m = (j <= iG) ? __expf(Gi - sG[j]) * accM[a][e] : 0.f;
          M_buf[(size_t)ch * 4096 + iG * 64 + j] = m;
        }
      }
      __syncthreads();
    }
  }

  {
    int ti = t >> 4, tj = t & 15;
    float accA[4][4];
    #pragma unroll
    for (int a = 0; a < 4; a++)
      #pragma unroll
      for (int e = 0; e < 4; e++) accA[a][e] = 0.f;
    for (int k4 = 0; k4 < 32; k4++) {
      float4 ki[4], kj[4];
      #pragma unroll
      for (int e = 0; e < 4; e++) {
        ki[e] = sK4[swf4(ti + 16 * e, k4)];
        kj[e] = sK4[swf4(tj + 16 * e, k4)];
      }
      #pragma unroll
      for (int a = 0; a < 4; a++)
        #pragma unroll
        for (int e = 0; e < 4; e++)
          accA[a][e] += ki[a].x * kj[e].x + ki[a].y * kj[e].y +
                        ki[a].z * kj[e].z + ki[a].w * kj[e].w;
    }
    float resA[4][4];
    #pragma unroll
    for (int a = 0; a < 4; a++) {
      int i = ti + 16 * a;
      float Gi = sG[i], Bi = sBe[i];
      #pragma unroll
      for (int e = 0; e < 4; e++) {
        int j = tj + 16 * e;
        resA[a][e] = (j < i) ? Bi * __expf(Gi - sG[j]) * accA[a][e] : 0.f;
      }
    }
    __syncthreads();
    #pragma unroll
    for (int a = 0; a < 4; a++)
      #pragma unroll
      for (int e = 0; e < 4; e++)
        sA[(ti + 16 * a) * 64 + (tj + 16 * e)] = resA[a][e];
  }
  __syncthreads();

  if (t < 64) {
    sT[t] = (t == 0) ? 1.f : 0.f;
    for (int i = 1; i < 64; i++) {
      float acc = 0.f;
      for (int j = 0; j < i; j++) acc += sA[i * 64 + j] * sT[j * 64 + t];
      sT[i * 64 + t] = ((t == i) ? 1.f : 0.f) - acc;
    }
    float w = Bw0 * __expf(Gw0);
    for (int j = 0; j < 64; j++) {
      float wj = __shfl(w, j);
      tTw[j * 64 + t] = sT[t * 64 + j] * wj;
    }
  }
  __syncthreads();

  {
    int i04 = t >> 4, tk = t & 15;
    float accK[4][8];
    #pragma unroll
    for (int r = 0; r < 4; r++)
      #pragma unroll
      for (int u = 0; u < 8; u++) accK[r][u] = 0.f;
    for (int j = 0; j < 64; j++) {
      float4 tw = ((float4*)tTw)[j * 16 + i04];
      #pragma unroll
      for (int u = 0; u < 8; u++) {
        float kv = sK[swf1(j, tk + 16 * u)];
        accK[0][u] += tw.x * kv; accK[1][u] += tw.y * kv;
        accK[2][u] += tw.z * kv; accK[3][u] += tw.w * kv;
      }
    }
    size_t base = (size_t)ch * NBIG;
    #pragma unroll
    for (int r = 0; r < 4; r++)
      #pragma unroll
      for (int u = 0; u < 8; u++)
        KcD[base + (i04 * 4 + r) * 128 + tk + 16 * u] = accK[r][u];
  }
  __syncthreads();

  if (t < 64) {
    for (int j = 0; j < 64; j++) {
      float bj = __shfl(Bw0, j);
      tTb[j * 64 + t] = sT[t * 64 + j] * bj;
    }
  }
  {
    const float4* src = (const float4*)(Vb + ((size_t)bh * S_ + s0) * DV_);
    #pragma unroll
    for (int u = 0; u < 8; u++) {
      int idx = u * 256 + t;
      sK4[swf4(idx >> 5, idx & 31)] = src[idx];
    }
  }
  __syncthreads();

  {
    int i04 = t >> 4, tv_ = t & 15;
    float accD[4][8];
    #pragma unroll
    for (int r = 0; r < 4; r++)
      #pragma unroll
      for (int u = 0; u < 8; u++) accD[r][u] = 0.f;
    for (int j = 0; j < 64; j++) {
      float4 tb = ((float4*)tTb)[j * 16 + i04];
      #pragma unroll
      for (int u = 0; u < 8; u++) {
        float vv = sK[swf1(j, tv_ + 16 * u)];
        accD[0][u] += tb.x * vv; accD[1][u] += tb.y * vv;
        accD[2][u] += tb.z * vv; accD[3][u] += tb.w * vv;
      }
    }
    size_t base = (size_t)ch * NBIG;
    #pragma unroll
    for (int r = 0; r < 4; r++)
      #pragma unroll
      for (int u = 0; u < 8; u++)
        D0p[base + (i04 * 4 + r) * 128 + tv_ + 16 * u] = accD[r][u];
  }
}

// ---------------------------------------------------------------------------
// phaseb v4: 256 blocks, XCD-swizzled; Kd LDS layout XOR-swizzled.
// ---------------------------------------------------------------------------
__global__ __launch_bounds__(256) void phaseb_kernel(
    const float* __restrict__ rec_state, const float* __restrict__ Qn,
    const float* __restrict__ Kn, const float* __restrict__ G_buf,
    float* __restrict__ KcD, const float* __restrict__ D0p,
    float* __restrict__ Oq_buf, float* __restrict__ final_state)
{
  __shared__ float sS[128 * 32];    // state [k][v]
  __shared__ float sKT[128 * 64];   // Kc^T [k][i]; then Kd (swizzled) [i][k]
  __shared__ float sQT[128 * 64];   // Qb^T [k][i]
  __shared__ float sD[64 * 32];     // D [i][v]

  const int blk = blockIdx.x;       // xcd | vq<<3 | g<<5
  const int bh = (blk & 7) | ((blk >> 5) << 3);
  const int vq = (blk >> 3) & 3;
  const int b = bh >> 5, hv = bh & 31, hk = hv >> 1;
  const int t = threadIdx.x;
  const int vbase = vq * 32;
  const float* gG = G_buf + (size_t)bh * S_;

  #pragma unroll
  for (int u = 0; u < 4; u++) {
    int idx = u * 256 + t;
    int k = idx >> 3;
    int v4 = (idx & 7) * 4;
    *(float4*)(&sS[k * 32 + v4]) =
        *(const float4*)(&rec_state[((size_t)bh * 128 + k) * 128 + vbase + v4]);
  }
  __syncthreads();

  const int si = t & 63, skq = t >> 6;
  const int ti = t >> 3;
  const int tv = t & 7;
  const int tk = t >> 3;

  for (int c = 0; c < NC_; c++) {
    const size_t ch = (size_t)bh * NC_ + c;
    const int s0 = c * CS_;
    const float GC = gG[s0 + 63];
    const float eGC = __expf(GC);

    {
      float eGi = __expf(gG[s0 + si]);
      const float* kcRow = KcD + ch * NBIG + si * 128 + skq * 32;
      const float* qRow  = Qn + ((size_t)(b * HK_ + hk) * S_ + s0 + si) * DK_ + skq * 32;
      #pragma unroll
      for (int u = 0; u < 8; u++) {
        float4 kc = *(const float4*)(kcRow + u * 4);
        float4 qv = *(const float4*)(qRow + u * 4);
        int kk = skq * 32 + u * 4;
        sKT[(kk + 0) * 64 + si] = kc.x; sKT[(kk + 1) * 64 + si] = kc.y;
        sKT[(kk + 2) * 64 + si] = kc.z; sKT[(kk + 3) * 64 + si] = kc.w;
        sQT[(kk + 0) * 64 + si] = qv.x * eGi; sQT[(kk + 1) * 64 + si] = qv.y * eGi;
        sQT[(kk + 2) * 64 + si] = qv.z * eGi; sQT[(kk + 3) * 64 + si] = qv.w * eGi;
      }
    }
    __syncthreads();

    {
      float accD[2][4], accO[2][4];
      #pragma unroll
      for (int r = 0; r < 2; r++) {
        float4 d0 = *(const float4*)(&D0p[ch * NBIG + (size_t)(ti * 2 + r) * 128 + vbase + tv * 4]);
        accD[r][0] = d0.x; accD[r][1] = d0.y; accD[r][2] = d0.z; accD[r][3] = d0.w;
        accO[r][0] = accO[r][1] = accO[r][2] = accO[r][3] = 0.f;
      }
      for (int k = 0; k < 128; k++) {
        float2 kc = *(const float2*)(&sKT[k * 64 + ti * 2]);
        float2 qb = *(const float2*)(&sQT[k * 64 + ti * 2]);
        float4 sv = *(const float4*)(&sS[k * 32 + tv * 4]);
        accD[0][0] -= kc.x * sv.x; accD[0][1] -= kc.x * sv.y;
        accD[0][2] -= kc.x * sv.z; accD[0][3] -= kc.x * sv.w;
        accD[1][0] -= kc.y * sv.x; accD[1][1] -= kc.y * sv.y;
        accD[1][2] -= kc.y * sv.z; accD[1][3] -= kc.y * sv.w;
        accO[0][0] += qb.x * sv.x; accO[0][1] += qb.x * sv.y;
        accO[0][2] += qb.x * sv.z; accO[0][3] += qb.x * sv.w;
        accO[1][0] += qb.y * sv.x; accO[1][1] += qb.y * sv.y;
        accO[1][2] += qb.y * sv.z; accO[1][3] += qb.y * sv.w;
      }
      #pragma unroll
      for (int r = 0; r < 2; r++) {
        int i = ti * 2 + r;
        float4 dv = make_float4(accD[r][0], accD[r][1], accD[r][2], accD[r][3]);
        float4 ov = make_float4(accO[r][0], accO[r][1], accO[r][2], accO[r][3]);
        *(float4*)(&sD[i * 32 + tv * 4]) = dv;
        *(float4*)(&KcD[ch * NBIG + (size_t)i * 128 + vbase + tv * 4]) = dv;
        *(float4*)(&Oq_buf[ch * 8192 + (size_t)i * 128 + vbase + tv * 4]) = ov;
      }
    }
    __syncthreads();

    {
      float sc = __expf(GC - gG[s0 + si]);
      const float* kRow = Kn + ((size_t)(b * HK_ + hk) * S_ + s0 + si) * DK_ + skq * 32;
      #pragma unroll
      for (int u = 0; u < 8; u++) {
        float4 x = *(const float4*)(kRow + u * 4);
        x.x *= sc; x.y *= sc; x.z *= sc; x.w *= sc;
        int kg = skq * 8 + u;
        *(float4*)(&sKT[si * 128 + 4 * (kg ^ (si & 31))]) = x;
      }
    }
    __syncthreads();

    {
      float acc[4][4];
      #pragma unroll
      for (int r = 0; r < 4; r++)
        acc[r][0] = acc[r][1] = acc[r][2] = acc[r][3] = 0.f;
      for (int i = 0; i < 64; i++) {
        float4 d  = *(const float4*)(&sD[i * 32 + tv * 4]);
        float4 ka = *(const float4*)(&sKT[i * 128 + 4 * (tk ^ (i & 31))]);
        acc[0][0] += ka.x * d.x; acc[0][1] += ka.x * d.y;
        acc[0][2] += ka.x * d.z; acc[0][3] += ka.x * d.w;
        acc[1][0] += ka.y * d.x; acc[1][1] += ka.y * d.y;
        acc[1][2] += ka.y * d.z; acc[1][3] += ka.y * d.w;
        acc[2][0] += ka.z * d.x; acc[2][1] += ka.z * d.y;
        acc[2][2] += ka.z * d.z; acc[2][3] += ka.z * d.w;
        acc[3][0] += ka.w * d.x; acc[3][1] += ka.w * d.y;
        acc[3][2] += ka.w * d.z; acc[3][3] += ka.w * d.w;
      }
      #pragma unroll
      for (int r = 0; r < 4; r++) {
        int k = tk * 4 + r;
        float4 s = *(const float4*)(&sS[k * 32 + tv * 4]);
        s.x = s.x * eGC + acc[r][0]; s.y = s.y * eGC + acc[r][1];
        s.z = s.z * eGC + acc[r][2]; s.w = s.w * eGC + acc[r][3];
        *(float4*)(&sS[k * 32 + tv * 4]) = s;
      }
    }
    __syncthreads();
  }

  #pragma unroll
  for (int u = 0; u < 4; u++) {
    int idx = u * 256 + t;
    int k = idx >> 3;
    int v4 = (idx & 7) * 4;
    *(float4*)(&final_state[((size_t)bh * 128 + k) * 128 + vbase + v4]) =
        *(const float4*)(&sS[k * 32 + v4]);
  }
}

// ---------------------------------------------------------------------------
// phasec: O = Oq + M*D, RMS-norm + weight + silu(z) gate -> bf16 zg
// ---------------------------------------------------------------------------
__global__ __launch_bounds__(128) void phasec_kernel(
    const float* __restrict__ KcD, const float* __restrict__ Oq_buf,
    const float* __restrict__ M_buf, const float* __restrict__ norm_weight,
    const float* __restrict__ Cbig, ushort* __restrict__ zg_bf)
{
  __shared__ float sM[4096];
  __shared__ float red[2][2];
  int ch = blockIdx.x;
  int bh = ch / NC_, c = ch % NC_;
  int b = bh >> 5, hv = bh & 31;
  int s0 = c * CS_;
  int v = threadIdx.x;

  float Dr[64];
  #pragma unroll
  for (int j = 0; j < 64; j++) Dr[j] = KcD[(size_t)ch * NBIG + j * 128 + v];
  {
    const float4* src = (const float4*)(M_buf + (size_t)ch * 4096);
    #pragma unroll
    for (int u = 0; u < 8; u++) ((float4*)sM)[u * 128 + v] = src[u * 128 + v];
  }
  __syncthreads();
  float nw = norm_weight[v];

  for (int i = 0; i < 64; i++) {
    float o = Oq_buf[(size_t)ch * 8192 + i * 128 + v];
    const float4* mr = (const float4*)(sM + i * 64);
    #pragma unroll
    for (int j4 = 0; j4 < 16; j4++) {
      float4 m = mr[j4];
      o += m.x * Dr[4 * j4] + m.y * Dr[4 * j4 + 1] +
           m.z * Dr[4 * j4 + 2] + m.w * Dr[4 * j4 + 3];
    }
    float p = o * o;
    #pragma unroll
    for (int off = 32; off > 0; off >>= 1) p += __shfl_xor(p, off);
    if ((v & 63) == 0) red[i & 1][v >> 6] = p;
    __syncthreads();
    float var = (red[i & 1][0] + red[i & 1][1]) * (1.f / 128.f);
    float xn = o * rsqrtf(var + 1e-6f) * nw;
    float zv = Cbig[((size_t)(b * S_ + s0 + i)) * NBIG + 8192 + hv * DV_ + v];
    zg_bf[((size_t)(b * S_ + s0 + i)) * VALDIM_ + hv * DV_ + v] =
        f2bf_rne(xn * (zv / (1.f + __expf(-zv))));
  }
}

// ---------------------------------------------------------------------------
extern "C" void kernel_launch(void* const* d_in, const int* in_sizes, int n_in,
                              void* d_out, int out_size, void* d_ws, size_t ws_size,
                              hipStream_t stream)
{
  const float* hs          = (const float*)d_in[0];
  const float* conv_state  = (const float*)d_in[1];
  const float* rec_state   = (const float*)d_in[2];
  const float* W_qkv       = (const float*)d_in[3];
  const float* W_z         = (const float*)d_in[4];
  const float* W_b         = (const float*)d_in[5];
  const float* W_a         = (const float*)d_in[6];
  const float* conv_w      = (const float*)d_in[7];
  const float* dt_bias     = (const float*)d_in[8];
  const float* A_log       = (const float*)d_in[9];
  const float* norm_weight = (const float*)d_in[10];
  const float* W_out       = (const float*)d_in[11];

  float* out       = (float*)d_out;                      // (B,S,H)
  float* out_conv  = out + (size_t)B_ * S_ * H_;         // (B,C,3)
  float* out_state = out_conv + (size_t)B_ * CC_ * 3;    // (B,HV,DK,DV)

  float* ws = (float*)d_ws;
  float* Cbig = ws;                            // (2048, 12416) = 25,427,968
  float* KcD  = Cbig;
  float* D0p  = Cbig + (size_t)1024 * NBIG;
  float* g_buf    = ws + 25427968;
  float* beta_buf = ws + 25493504;
  float* G_buf    = ws + 25559040;
  float* Qn       = ws + 25624576;
  float* Kn       = ws + 29818880;
  float* Vb       = ws + 34013184;
  float* M_buf    = ws + 42401792;
  float* Oq_buf   = Vb;

  ushort* Wcat_bf = (ushort*)(ws + 25427968);
  ushort* hs_bf   = (ushort*)(ws + 38141952);
  ushort* zg_bf   = (ushort*)Qn;
  ushort* Wout_bf = (ushort*)Kn;

  const int M = B_ * S_;  // 2048

  // 0. converts
  f2bf_kernel<<<(M * H_) / 1024, 256, 0, stream>>>(hs, hs_bf, M * H_);
  wcat_kernel<<<(NBIG * H_) / 1024, 256, 0, stream>>>(W_qkv, W_z, W_b, W_a, Wcat_bf);
  // 1. fused qkv|z|b|a GEMM -> Cbig (dbuf BK=32, 5 blk/CU, XCD n-grouping)
  gemm_bf16_nt<<<8 * 16 * ((NBIG / 128 + 7) / 8), 256, 0, stream>>>(
      hs_bf, Wcat_bf, Cbig, NBIG, H_, NBIG / 128);
  // 2. conv_state_new output
  convstate_kernel<<<(B_ * CC_ * 3 + 255) / 256, 256, 0, stream>>>(Cbig, out_conv);
  // 3. conv+silu+l2norm -> Qn,Kn,Vb ; gates
  prep_qkv<<<dim3(64, S_, B_), 128, 0, stream>>>(Cbig, conv_state, conv_w, Qn, Kn, Vb);
  prep_gb<<<(B_ * HV_ * S_ + 255) / 256, 256, 0, stream>>>(Cbig, A_log, dt_bias, g_buf, beta_buf);
  // 4. per-chunk matrices
  cp_kernel<<<B_ * HV_ * NC_, 256, 0, stream>>>(Qn, Kn, Vb, g_buf, beta_buf,
                                                G_buf, M_buf, KcD, D0p);
  // 5. sequential chunk recurrence
  phaseb_kernel<<<B_ * HV_ * 4, 256, 0, stream>>>(rec_state, Qn, Kn, G_buf,
                                                  KcD, D0p, Oq_buf, out_state);
  // 6. W_out convert + intra-chunk output/RMS/gate -> bf16
  f2bf_kernel<<<(H_ * VALDIM_) / 1024, 256, 0, stream>>>(W_out, Wout_bf, H_ * VALDIM_);
  phasec_kernel<<<B_ * HV_ * NC_, 128, 0, stream>>>(KcD, Oq_buf, M_buf,
                                                    norm_weight, Cbig, zg_bf);
  // 7. output GEMM
  gemm_bf16_nt<<<8 * 16 * ((H_ / 128 + 7) / 8), 256, 0, stream>>>(
      zg_bf, Wout_bf, out, H_, VALDIM_, H_ / 128);
}